// Round 2
// baseline (5401.574 us; speedup 1.0000x reference)
//
#include <hip/hip_runtime.h>
#include <cstddef>

// Problem dims (fixed by the reference)
#define Bx 32
#define Sx 2048
#define Hx 256
#define Lx 2

// ------------------------------------------------------------------
// GEMM: C[m,n] = sum_k A[m,k] * W[n,k] + bias[n]
// A: [M, 256] row-major, W: [256, 256] row-major (N-major), C: [M, 256]
// BM=64, BN=64, BK=32, 256 threads, 4x4 microtile per thread.
// ------------------------------------------------------------------
#define GBM 64
#define GBN 64
#define GBK 32

__global__ __launch_bounds__(256) void gemm_xp(
    const float* __restrict__ A,
    const float* __restrict__ W,
    const float* __restrict__ bias,
    float* __restrict__ C)
{
    __shared__ float As[GBK][GBM + 1];   // +1 pad: conflict-free transposed stores
    __shared__ float Ws[GBK][GBN + 1];

    const int tid = threadIdx.x;
    const int tx  = tid & 15;        // 0..15  -> N direction
    const int ty  = tid >> 4;        // 0..15  -> M direction
    const int m0  = blockIdx.x * GBM;
    const int n0  = blockIdx.y * GBN;
    const int r   = tid >> 3;        // 0..31  loader row
    const int c4  = tid & 7;         // 0..7   loader float4-col

    float acc[4][4] = {};

    for (int k0 = 0; k0 < Hx; k0 += GBK) {
        // global loads into registers (don't touch LDS yet)
        const float4 a0 = *(const float4*)(A + (size_t)(m0 + r)      * Hx + k0 + c4 * 4);
        const float4 a1 = *(const float4*)(A + (size_t)(m0 + r + 32) * Hx + k0 + c4 * 4);
        const float4 w0 = *(const float4*)(W + (size_t)(n0 + r)      * Hx + k0 + c4 * 4);
        const float4 w1 = *(const float4*)(W + (size_t)(n0 + r + 32) * Hx + k0 + c4 * 4);

        __syncthreads();   // previous tile fully consumed before overwrite

        As[c4 * 4 + 0][r] = a0.x;  As[c4 * 4 + 1][r] = a0.y;
        As[c4 * 4 + 2][r] = a0.z;  As[c4 * 4 + 3][r] = a0.w;
        As[c4 * 4 + 0][r + 32] = a1.x;  As[c4 * 4 + 1][r + 32] = a1.y;
        As[c4 * 4 + 2][r + 32] = a1.z;  As[c4 * 4 + 3][r + 32] = a1.w;

        Ws[c4 * 4 + 0][r] = w0.x;  Ws[c4 * 4 + 1][r] = w0.y;
        Ws[c4 * 4 + 2][r] = w0.z;  Ws[c4 * 4 + 3][r] = w0.w;
        Ws[c4 * 4 + 0][r + 32] = w1.x;  Ws[c4 * 4 + 1][r + 32] = w1.y;
        Ws[c4 * 4 + 2][r + 32] = w1.z;  Ws[c4 * 4 + 3][r + 32] = w1.w;

        __syncthreads();

        #pragma unroll
        for (int k = 0; k < GBK; ++k) {
            float av[4], wv[4];
            #pragma unroll
            for (int i = 0; i < 4; ++i) av[i] = As[k][ty * 4 + i];
            #pragma unroll
            for (int j = 0; j < 4; ++j) wv[j] = Ws[k][tx * 4 + j];
            #pragma unroll
            for (int i = 0; i < 4; ++i)
                #pragma unroll
                for (int j = 0; j < 4; ++j)
                    acc[i][j] = fmaf(av[i], wv[j], acc[i][j]);
        }
    }

    const float4 bv = *(const float4*)(bias + n0 + tx * 4);
    #pragma unroll
    for (int i = 0; i < 4; ++i) {
        float4 o;
        o.x = acc[i][0] + bv.x;
        o.y = acc[i][1] + bv.y;
        o.z = acc[i][2] + bv.z;
        o.w = acc[i][3] + bv.w;
        *(float4*)(C + (size_t)(m0 + ty * 4 + i) * Hx + n0 + tx * 4) = o;
    }
}

// ------------------------------------------------------------------
// Recurrence: one workgroup per batch element; 512 threads (8 waves).
// Thread t: output index h = t>>1, reduction half = t&1.
// W_hh row-half (128 floats = 32 float4) lives in VGPRs. h state
// double-buffered in LDS; ONE __syncthreads per step (write goes to the
// buffer nobody reads this step). xp prefetched 2 steps ahead to cover
// L3/HBM latency (~600-900 cy) against a ~550-cy step.
// ------------------------------------------------------------------
__global__ __launch_bounds__(512) void rnn_scan(
    const float* __restrict__ xp,    // [B,S,H] precomputed x@W_ih^T + b_ih
    const float* __restrict__ h0l,   // [B,H]   initial hidden for this layer
    const float* __restrict__ Whh,   // [H,H]
    const float* __restrict__ bhh,   // [H]
    float* __restrict__ y,           // [B,S,H] layer output
    float* __restrict__ hfin)        // [B,H]   final hidden for this layer
{
    const int b    = blockIdx.x;
    const int t    = threadIdx.x;
    const int h    = t >> 1;
    const int half = t & 1;

    // 128 weights per thread in registers (32 x float4, fully unrolled -> VGPRs)
    float4 w[32];
    const float4* wrow = (const float4*)(Whh + (size_t)h * Hx + half * 128);
    #pragma unroll
    for (int j = 0; j < 32; ++j) w[j] = wrow[j];

    __shared__ float hs[2][Hx];
    if (t < Hx) hs[0][t] = h0l[(size_t)b * Hx + t];
    const float bias = bhh[h];
    __syncthreads();

    const float* xpb = xp + (size_t)b * Sx * Hx;
    float*       yb  = y  + (size_t)b * Sx * Hx;

    // 2-deep prefetch pipeline for the per-step xp value
    float xv_n1 = xpb[h];                      // s = 0
    float xv_n2 = xpb[(size_t)Hx + h];         // s = 1
    float hnew  = 0.0f;
    int   cur   = 0;

    for (int s = 0; s < Sx; ++s) {
        const float xv = xv_n1;
        xv_n1 = xv_n2;
        if (s + 2 < Sx) xv_n2 = xpb[(size_t)(s + 2) * Hx + h];  // in flight ~2 steps

        const float4* hv = (const float4*)(hs[cur] + half * 128);
        float4 acc = make_float4(0.f, 0.f, 0.f, 0.f);
        #pragma unroll
        for (int j = 0; j < 32; ++j) {
            const float4 hh = hv[j];           // 2-address broadcast LDS read (free)
            acc.x = fmaf(w[j].x, hh.x, acc.x); // 4 independent accumulator chains
            acc.y = fmaf(w[j].y, hh.y, acc.y);
            acc.z = fmaf(w[j].z, hh.z, acc.z);
            acc.w = fmaf(w[j].w, hh.w, acc.w);
        }
        float sum = (acc.x + acc.y) + (acc.z + acc.w);
        sum += __shfl_xor(sum, 1);             // pair-reduce across the two halves

        hnew = tanhf(xv + sum + bias);

        if (!half) {
            hs[cur ^ 1][h] = hnew;             // write OTHER buffer: one barrier suffices
            yb[(size_t)s * Hx + h] = hnew;     // fire-and-forget layer output
        }
        cur ^= 1;
        __syncthreads();
    }

    if (!half) hfin[(size_t)b * Hx + h] = hnew;
}

// ------------------------------------------------------------------
// Launch: GEMM(l0) -> scan(l0) -> GEMM(l1) -> scan(l1), stream-ordered.
// ws: xp buffer (64 MB). d_out[0:B*S*H] doubles as y1 scratch before being
// overwritten by the layer-2 scan (we fully rewrite d_out every call; the
// harness re-poisons it before each timed launch anyway).
// ------------------------------------------------------------------
extern "C" void kernel_launch(void* const* d_in, const int* in_sizes, int n_in,
                              void* d_out, int out_size, void* d_ws, size_t ws_size,
                              hipStream_t stream) {
    const float* x    = (const float*)d_in[0];   // [B,S,H]
    const float* h0   = (const float*)d_in[1];   // [L,B,H]
    const float* W_ih = (const float*)d_in[2];   // [L,H,H]
    const float* W_hh = (const float*)d_in[3];   // [L,H,H]
    const float* b_ih = (const float*)d_in[4];   // [L,H]
    const float* b_hh = (const float*)d_in[5];   // [L,H]

    float* out    = (float*)d_out;                       // [B,S,H]
    float* finals = out + (size_t)Bx * Sx * Hx;          // [L,B,H]
    float* xp     = (float*)d_ws;                        // [B,S,H] scratch (64 MB)

    const dim3 ggrid(Bx * Sx / GBM, Hx / GBN);           // (1024, 4)

    // Layer 0
    gemm_xp<<<ggrid, 256, 0, stream>>>(x, W_ih, b_ih, xp);
    rnn_scan<<<Bx, 512, 0, stream>>>(xp, h0, W_hh, b_hh,
                                     out /* y1 scratch */, finals);
    // Layer 1
    gemm_xp<<<ggrid, 256, 0, stream>>>(out, W_ih + Hx * Hx, b_ih + Hx, xp);
    rnn_scan<<<Bx, 512, 0, stream>>>(xp, h0 + (size_t)Bx * Hx,
                                     W_hh + Hx * Hx, b_hh + Hx,
                                     out, finals + (size_t)Bx * Hx);
}

// Round 3
// 4444.953 us; speedup vs baseline: 1.2152x; 1.2152x over previous
//
#include <hip/hip_runtime.h>
#include <cstddef>

// Problem dims (fixed by the reference)
#define Bx 32
#define Sx 2048
#define Hx 256
#define Lx 2

// ------------------------------------------------------------------
// GEMM: C[m,n] = sum_k A[m,k] * W[n,k] + bias[n]
// A: [M, 256] row-major, W: [256, 256] row-major (N-major), C: [M, 256]
// BM=64, BN=64, BK=32, 256 threads, 4x4 microtile per thread.
// (not the bottleneck: ~200 us each vs 2487 us scans; untouched this round)
// ------------------------------------------------------------------
#define GBM 64
#define GBN 64
#define GBK 32

__global__ __launch_bounds__(256) void gemm_xp(
    const float* __restrict__ A,
    const float* __restrict__ W,
    const float* __restrict__ bias,
    float* __restrict__ C)
{
    __shared__ float As[GBK][GBM + 1];
    __shared__ float Ws[GBK][GBN + 1];

    const int tid = threadIdx.x;
    const int tx  = tid & 15;
    const int ty  = tid >> 4;
    const int m0  = blockIdx.x * GBM;
    const int n0  = blockIdx.y * GBN;
    const int r   = tid >> 3;
    const int c4  = tid & 7;

    float acc[4][4] = {};

    for (int k0 = 0; k0 < Hx; k0 += GBK) {
        const float4 a0 = *(const float4*)(A + (size_t)(m0 + r)      * Hx + k0 + c4 * 4);
        const float4 a1 = *(const float4*)(A + (size_t)(m0 + r + 32) * Hx + k0 + c4 * 4);
        const float4 w0 = *(const float4*)(W + (size_t)(n0 + r)      * Hx + k0 + c4 * 4);
        const float4 w1 = *(const float4*)(W + (size_t)(n0 + r + 32) * Hx + k0 + c4 * 4);

        __syncthreads();

        As[c4 * 4 + 0][r] = a0.x;  As[c4 * 4 + 1][r] = a0.y;
        As[c4 * 4 + 2][r] = a0.z;  As[c4 * 4 + 3][r] = a0.w;
        As[c4 * 4 + 0][r + 32] = a1.x;  As[c4 * 4 + 1][r + 32] = a1.y;
        As[c4 * 4 + 2][r + 32] = a1.z;  As[c4 * 4 + 3][r + 32] = a1.w;

        Ws[c4 * 4 + 0][r] = w0.x;  Ws[c4 * 4 + 1][r] = w0.y;
        Ws[c4 * 4 + 2][r] = w0.z;  Ws[c4 * 4 + 3][r] = w0.w;
        Ws[c4 * 4 + 0][r + 32] = w1.x;  Ws[c4 * 4 + 1][r + 32] = w1.y;
        Ws[c4 * 4 + 2][r + 32] = w1.z;  Ws[c4 * 4 + 3][r + 32] = w1.w;

        __syncthreads();

        #pragma unroll
        for (int k = 0; k < GBK; ++k) {
            float av[4], wv[4];
            #pragma unroll
            for (int i = 0; i < 4; ++i) av[i] = As[k][ty * 4 + i];
            #pragma unroll
            for (int j = 0; j < 4; ++j) wv[j] = Ws[k][tx * 4 + j];
            #pragma unroll
            for (int i = 0; i < 4; ++i)
                #pragma unroll
                for (int j = 0; j < 4; ++j)
                    acc[i][j] = fmaf(av[i], wv[j], acc[i][j]);
        }
    }

    const float4 bv = *(const float4*)(bias + n0 + tx * 4);
    #pragma unroll
    for (int i = 0; i < 4; ++i) {
        float4 o;
        o.x = acc[i][0] + bv.x;
        o.y = acc[i][1] + bv.y;
        o.z = acc[i][2] + bv.z;
        o.w = acc[i][3] + bv.w;
        *(float4*)(C + (size_t)(m0 + ty * 4 + i) * Hx + n0 + tx * 4) = o;
    }
}

// ------------------------------------------------------------------
// Recurrence v2: one WG per batch, 512 threads, 1 barrier/step.
//
// Round-2 evidence: VGPR=84 (weights NOT resident -> reloaded every step,
// VALUBusy 55%/CU) and SQ_LDS_BANK_CONFLICT = 1024 cyc/WG/step (LDS delivery
// floor: 256KB/step at 1 h-byte read per MAC, 2 addrs aliasing same banks).
//
// Fixes:
//  * __launch_bounds__(512, 2): 1 block/CU -> 256-VGPR budget -> wq[4][8]
//    (128 VGPRs of weights) stays register-resident.
//  * thread t -> output quad g=t>>3 (4 rows), k-slice ks=t&7 (32 k each):
//    4x reuse of every h value read -> LDS h-traffic 256KB -> 64KB/step.
//  * ks-rotated reads: at unrolled step j, lane ks reads float4 at float
//    offset ks*32 + ((j+ks)&7)*4 -> the 8 distinct addresses per wave hit
//    8 distinct bank-groups -> conflict-free. Weights pre-rotated at load
//    time so ALL register indexing is compile-time static (no scratch).
//  * 8-lane shfl_xor butterfly (masks 1,2,4) reduces the k-split.
// ------------------------------------------------------------------
__global__ __launch_bounds__(512, 2) void rnn_scan(
    const float* __restrict__ xp,    // [B,S,H] precomputed x@W_ih^T + b_ih
    const float* __restrict__ h0l,   // [B,H]
    const float* __restrict__ Whh,   // [H,H]
    const float* __restrict__ bhh,   // [H]
    float* __restrict__ y,           // [B,S,H]
    float* __restrict__ hfin)        // [B,H]
{
    const int b   = blockIdx.x;
    const int t   = threadIdx.x;
    const int g   = t >> 3;          // 0..63 output quad
    const int ks  = t & 7;           // 0..7  k-slice
    const int out = g * 4 + (ks & 3);            // output index this lane handles
    const bool writer = (ks < 4);                // lanes 0..3 of each group write

    // Weights: wq[o][j] = Whh[g*4+o][ks*32 + ((j+ks)&7)*4 .. +3]
    // 32 float4 = 128 VGPRs; register index (o,j) fully static.
    float4 wq[4][8];
    #pragma unroll
    for (int o = 0; o < 4; ++o) {
        const float* wrow = Whh + (size_t)(g * 4 + o) * Hx + ks * 32;
        #pragma unroll
        for (int j = 0; j < 8; ++j)
            wq[o][j] = *(const float4*)(wrow + ((j + ks) & 7) * 4);
    }

    __shared__ float hs[2][Hx];
    if (t < Hx) hs[0][t] = h0l[(size_t)b * Hx + t];
    const float bias = bhh[out];
    __syncthreads();

    const float* xpb = xp + (size_t)b * Sx * Hx;
    float*       yb  = y  + (size_t)b * Sx * Hx;

    // 2-deep xp prefetch (covers L3/HBM latency against ~1000-cy steps)
    float xv_n1 = xpb[out];
    float xv_n2 = xpb[(size_t)Hx + out];
    float hnew  = 0.0f;
    int   cur   = 0;

    const int rotbase = ks * 128;    // byte offset of this lane's k-slice in hs

    for (int s = 0; s < Sx; ++s) {
        const float xv = xv_n1;
        xv_n1 = xv_n2;
        if (s + 2 < Sx) xv_n2 = xpb[(size_t)(s + 2) * Hx + out];

        // 8 rotated, conflict-free b128 reads of this lane's 128-float slice
        const char* hbase = (const char*)(hs[cur]) + rotbase;
        float4 h4[8];
        #pragma unroll
        for (int j = 0; j < 8; ++j)
            h4[j] = *(const float4*)(hbase + (((j + ks) & 7) << 4));

        float4 a0 = make_float4(0.f,0.f,0.f,0.f);
        float4 a1 = make_float4(0.f,0.f,0.f,0.f);
        float4 a2 = make_float4(0.f,0.f,0.f,0.f);
        float4 a3 = make_float4(0.f,0.f,0.f,0.f);
        #pragma unroll
        for (int j = 0; j < 8; ++j) {
            const float4 hh = h4[j];
            a0.x = fmaf(wq[0][j].x, hh.x, a0.x);
            a0.y = fmaf(wq[0][j].y, hh.y, a0.y);
            a0.z = fmaf(wq[0][j].z, hh.z, a0.z);
            a0.w = fmaf(wq[0][j].w, hh.w, a0.w);
            a1.x = fmaf(wq[1][j].x, hh.x, a1.x);
            a1.y = fmaf(wq[1][j].y, hh.y, a1.y);
            a1.z = fmaf(wq[1][j].z, hh.z, a1.z);
            a1.w = fmaf(wq[1][j].w, hh.w, a1.w);
            a2.x = fmaf(wq[2][j].x, hh.x, a2.x);
            a2.y = fmaf(wq[2][j].y, hh.y, a2.y);
            a2.z = fmaf(wq[2][j].z, hh.z, a2.z);
            a2.w = fmaf(wq[2][j].w, hh.w, a2.w);
            a3.x = fmaf(wq[3][j].x, hh.x, a3.x);
            a3.y = fmaf(wq[3][j].y, hh.y, a3.y);
            a3.z = fmaf(wq[3][j].z, hh.z, a3.z);
            a3.w = fmaf(wq[3][j].w, hh.w, a3.w);
        }
        float s0 = (a0.x + a0.y) + (a0.z + a0.w);
        float s1 = (a1.x + a1.y) + (a1.z + a1.w);
        float s2 = (a2.x + a2.y) + (a2.z + a2.w);
        float s3 = (a3.x + a3.y) + (a3.z + a3.w);

        // butterfly over the 8-lane group: all lanes end with all 4 sums
        s0 += __shfl_xor(s0, 1);  s1 += __shfl_xor(s1, 1);
        s2 += __shfl_xor(s2, 1);  s3 += __shfl_xor(s3, 1);
        s0 += __shfl_xor(s0, 2);  s1 += __shfl_xor(s1, 2);
        s2 += __shfl_xor(s2, 2);  s3 += __shfl_xor(s3, 2);
        s0 += __shfl_xor(s0, 4);  s1 += __shfl_xor(s1, 4);
        s2 += __shfl_xor(s2, 4);  s3 += __shfl_xor(s3, 4);

        // static 2-level select of this lane's output sum (no runtime reg index)
        const float sa  = (ks & 1) ? s1 : s0;
        const float sc  = (ks & 1) ? s3 : s2;
        const float sel = (ks & 2) ? sc : sa;

        hnew = tanhf(xv + sel + bias);

        if (writer) {
            hs[cur ^ 1][out] = hnew;          // other buffer: one barrier suffices
            yb[(size_t)s * Hx + out] = hnew;  // fire-and-forget layer output
        }
        cur ^= 1;
        __syncthreads();
    }

    if (writer) hfin[(size_t)b * Hx + out] = hnew;
}

// ------------------------------------------------------------------
// Launch: GEMM(l0) -> scan(l0) -> GEMM(l1) -> scan(l1), stream-ordered.
// ws: xp scratch (64 MB). d_out[0:B*S*H] doubles as y1 scratch before the
// layer-2 scan overwrites it (we fully rewrite d_out every call).
// ------------------------------------------------------------------
extern "C" void kernel_launch(void* const* d_in, const int* in_sizes, int n_in,
                              void* d_out, int out_size, void* d_ws, size_t ws_size,
                              hipStream_t stream) {
    const float* x    = (const float*)d_in[0];   // [B,S,H]
    const float* h0   = (const float*)d_in[1];   // [L,B,H]
    const float* W_ih = (const float*)d_in[2];   // [L,H,H]
    const float* W_hh = (const float*)d_in[3];   // [L,H,H]
    const float* b_ih = (const float*)d_in[4];   // [L,H]
    const float* b_hh = (const float*)d_in[5];   // [L,H]

    float* out    = (float*)d_out;                       // [B,S,H]
    float* finals = out + (size_t)Bx * Sx * Hx;          // [L,B,H]
    float* xp     = (float*)d_ws;                        // [B,S,H] scratch

    const dim3 ggrid(Bx * Sx / GBM, Hx / GBN);           // (1024, 4)

    // Layer 0
    gemm_xp<<<ggrid, 256, 0, stream>>>(x, W_ih, b_ih, xp);
    rnn_scan<<<Bx, 512, 0, stream>>>(xp, h0, W_hh, b_hh,
                                     out /* y1 scratch */, finals);
    // Layer 1
    gemm_xp<<<ggrid, 256, 0, stream>>>(out, W_ih + Hx * Hx, b_ih + Hx, xp);
    rnn_scan<<<Bx, 512, 0, stream>>>(xp, h0 + (size_t)Bx * Hx,
                                     W_hh + Hx * Hx, b_hh + Hx,
                                     out, finals + (size_t)Bx * Hx);
}

// Round 4
// 3832.145 us; speedup vs baseline: 1.4095x; 1.1599x over previous
//
#include <hip/hip_runtime.h>
#include <cstddef>

// Problem dims (fixed by the reference)
#define Bx 32
#define Sx 2048
#define Hx 256
#define Lx 2

// ------------------------------------------------------------------
// GEMM: C[m,n] = sum_k A[m,k] * W[n,k] + bias[n]   (unchanged; ~180 us,
// not the bottleneck while scans are >750 us)
// ------------------------------------------------------------------
#define GBM 64
#define GBN 64
#define GBK 32

__global__ __launch_bounds__(256) void gemm_xp(
    const float* __restrict__ A,
    const float* __restrict__ W,
    const float* __restrict__ bias,
    float* __restrict__ C)
{
    __shared__ float As[GBK][GBM + 1];
    __shared__ float Ws[GBK][GBN + 1];

    const int tid = threadIdx.x;
    const int tx  = tid & 15;
    const int ty  = tid >> 4;
    const int m0  = blockIdx.x * GBM;
    const int n0  = blockIdx.y * GBN;
    const int r   = tid >> 3;
    const int c4  = tid & 7;

    float acc[4][4] = {};

    for (int k0 = 0; k0 < Hx; k0 += GBK) {
        const float4 a0 = *(const float4*)(A + (size_t)(m0 + r)      * Hx + k0 + c4 * 4);
        const float4 a1 = *(const float4*)(A + (size_t)(m0 + r + 32) * Hx + k0 + c4 * 4);
        const float4 w0 = *(const float4*)(W + (size_t)(n0 + r)      * Hx + k0 + c4 * 4);
        const float4 w1 = *(const float4*)(W + (size_t)(n0 + r + 32) * Hx + k0 + c4 * 4);

        __syncthreads();

        As[c4 * 4 + 0][r] = a0.x;  As[c4 * 4 + 1][r] = a0.y;
        As[c4 * 4 + 2][r] = a0.z;  As[c4 * 4 + 3][r] = a0.w;
        As[c4 * 4 + 0][r + 32] = a1.x;  As[c4 * 4 + 1][r + 32] = a1.y;
        As[c4 * 4 + 2][r + 32] = a1.z;  As[c4 * 4 + 3][r + 32] = a1.w;

        Ws[c4 * 4 + 0][r] = w0.x;  Ws[c4 * 4 + 1][r] = w0.y;
        Ws[c4 * 4 + 2][r] = w0.z;  Ws[c4 * 4 + 3][r] = w0.w;
        Ws[c4 * 4 + 0][r + 32] = w1.x;  Ws[c4 * 4 + 1][r + 32] = w1.y;
        Ws[c4 * 4 + 2][r + 32] = w1.z;  Ws[c4 * 4 + 3][r + 32] = w1.w;

        __syncthreads();

        #pragma unroll
        for (int k = 0; k < GBK; ++k) {
            float av[4], wv[4];
            #pragma unroll
            for (int i = 0; i < 4; ++i) av[i] = As[k][ty * 4 + i];
            #pragma unroll
            for (int j = 0; j < 4; ++j) wv[j] = Ws[k][tx * 4 + j];
            #pragma unroll
            for (int i = 0; i < 4; ++i)
                #pragma unroll
                for (int j = 0; j < 4; ++j)
                    acc[i][j] = fmaf(av[i], wv[j], acc[i][j]);
        }
    }

    const float4 bv = *(const float4*)(bias + n0 + tx * 4);
    #pragma unroll
    for (int i = 0; i < 4; ++i) {
        float4 o;
        o.x = acc[i][0] + bv.x;
        o.y = acc[i][1] + bv.y;
        o.z = acc[i][2] + bv.z;
        o.w = acc[i][3] + bv.w;
        *(float4*)(C + (size_t)(m0 + ty * 4 + i) * Hx + n0 + tx * 4) = o;
    }
}

// ------------------------------------------------------------------
// DPP butterfly helpers: reduction entirely on the VALU (no DS pipe).
//   xor1 : quad_perm [1,0,3,2] -> ctrl 0xB1
//   xor2 : quad_perm [2,3,0,1] -> ctrl 0x4E
//   xor8 : row_ror:8           -> ctrl 0x128  (rotate by 8 within 16 = xor8)
// ------------------------------------------------------------------
template <int CTRL>
__device__ __forceinline__ float dpp_xadd(float x) {
    int xi = __builtin_bit_cast(int, x);
    int yi = __builtin_amdgcn_update_dpp(0, xi, CTRL, 0xF, 0xF, true);
    return x + __builtin_bit_cast(float, yi);
}
__device__ __forceinline__ float red8(float s) {
    s = dpp_xadd<0xB1>(s);    // + lane^1
    s = dpp_xadd<0x4E>(s);    // + lane^2
    s = dpp_xadd<0x128>(s);   // + lane^8
    return s;
}

// ------------------------------------------------------------------
// Recurrence v3: one WG per batch, 512 threads, 1 barrier/step.
//
// Round-3 evidence: bank conflicts 0 (rotation works), but VGPR=104 ->
// weights still reloaded every step (RA targeted ~5 waves/EU = ~102 regs
// and rematerialized). Also the 12 __shfl_xor/thread are ds_swizzle ->
// they share the DS pipe with the 8 ds_read_b128 (~768 + ~600 cyc/step).
//
// Fixes:
//  * amdgpu_waves_per_eu(2,2): pin exactly 2 waves/SIMD -> 256-VGPR
//    budget -> wq[4][8] (128 VGPRs) must stay resident. Grid is only
//    32 WGs on 256 CUs, so capping occupancy costs nothing.
//  * k-group remapped to lane bits {0,1,3}: butterfly = 3 DPP adds on
//    the VALU (quad_perm/row_ror), freeing ~600 cyc/step of DS pipe.
//    (outputs-within-wave now live on lane bits {2,4,5}.)
// ------------------------------------------------------------------
__global__ __launch_bounds__(512)
__attribute__((amdgpu_waves_per_eu(2, 2)))
void rnn_scan(
    const float* __restrict__ xp,    // [B,S,H] precomputed x@W_ih^T + b_ih
    const float* __restrict__ h0l,   // [B,H]
    const float* __restrict__ Whh,   // [H,H]
    const float* __restrict__ bhh,   // [H]
    float* __restrict__ y,           // [B,S,H]
    float* __restrict__ hfin)        // [B,H]
{
    const int b    = blockIdx.x;
    const int t    = threadIdx.x;
    const int lane = t & 63;
    const int wid  = t >> 6;                               // wave id 0..7
    const int ks   = (lane & 3) | ((lane >> 1) & 4);       // k-slice: bits {0,1,3}
    const int gw   = ((lane >> 2) & 1) | ((lane >> 3) & 6);// group-in-wave: bits {2,4,5}
    const int g    = wid * 8 + gw;                         // output quad 0..63
    const int out  = g * 4 + (lane & 3);                   // output this lane finalizes
    const bool writer = (lane & 8) == 0;                   // ks < 4

    // Weights: wq[o][j] = Whh[g*4+o][ks*32 + ((j+ks)&7)*4 .. +3]
    // (pre-rotated so the LDS h-reads below are conflict-free with static
    //  register indexing). 32 float4 = 128 VGPRs, pinned by waves_per_eu.
    float4 wq[4][8];
    #pragma unroll
    for (int o = 0; o < 4; ++o) {
        const float* wrow = Whh + (size_t)(g * 4 + o) * Hx + ks * 32;
        #pragma unroll
        for (int j = 0; j < 8; ++j)
            wq[o][j] = *(const float4*)(wrow + ((j + ks) & 7) * 4);
    }

    __shared__ float hs[2][Hx];
    if (t < Hx) hs[0][t] = h0l[(size_t)b * Hx + t];
    const float bias = bhh[out];
    __syncthreads();

    const float* xpb = xp + (size_t)b * Sx * Hx;
    float*       yb  = y  + (size_t)b * Sx * Hx;

    // 2-deep xp prefetch (covers L2/HBM latency against ~900-cy steps)
    float xv_n1 = xpb[out];
    float xv_n2 = xpb[(size_t)Hx + out];
    float hnew  = 0.0f;
    int   cur   = 0;

    const int rotbase = ks * 128;    // byte offset of this lane's k-slice in hs

    for (int s = 0; s < Sx; ++s) {
        const float xv = xv_n1;
        xv_n1 = xv_n2;
        if (s + 2 < Sx) xv_n2 = xpb[(size_t)(s + 2) * Hx + out];

        // 8 rotated, conflict-free ds_read_b128 of this lane's 128-float slice
        const char* hbase = (const char*)(hs[cur]) + rotbase;
        float4 h4[8];
        #pragma unroll
        for (int j = 0; j < 8; ++j)
            h4[j] = *(const float4*)(hbase + (((j + ks) & 7) << 4));

        float4 a0 = make_float4(0.f,0.f,0.f,0.f);
        float4 a1 = make_float4(0.f,0.f,0.f,0.f);
        float4 a2 = make_float4(0.f,0.f,0.f,0.f);
        float4 a3 = make_float4(0.f,0.f,0.f,0.f);
        #pragma unroll
        for (int j = 0; j < 8; ++j) {
            const float4 hh = h4[j];
            a0.x = fmaf(wq[0][j].x, hh.x, a0.x);
            a0.y = fmaf(wq[0][j].y, hh.y, a0.y);
            a0.z = fmaf(wq[0][j].z, hh.z, a0.z);
            a0.w = fmaf(wq[0][j].w, hh.w, a0.w);
            a1.x = fmaf(wq[1][j].x, hh.x, a1.x);
            a1.y = fmaf(wq[1][j].y, hh.y, a1.y);
            a1.z = fmaf(wq[1][j].z, hh.z, a1.z);
            a1.w = fmaf(wq[1][j].w, hh.w, a1.w);
            a2.x = fmaf(wq[2][j].x, hh.x, a2.x);
            a2.y = fmaf(wq[2][j].y, hh.y, a2.y);
            a2.z = fmaf(wq[2][j].z, hh.z, a2.z);
            a2.w = fmaf(wq[2][j].w, hh.w, a2.w);
            a3.x = fmaf(wq[3][j].x, hh.x, a3.x);
            a3.y = fmaf(wq[3][j].y, hh.y, a3.y);
            a3.z = fmaf(wq[3][j].z, hh.z, a3.z);
            a3.w = fmaf(wq[3][j].w, hh.w, a3.w);
        }
        float s0 = (a0.x + a0.y) + (a0.z + a0.w);
        float s1 = (a1.x + a1.y) + (a1.z + a1.w);
        float s2 = (a2.x + a2.y) + (a2.z + a2.w);
        float s3 = (a3.x + a3.y) + (a3.z + a3.w);

        // VALU-only butterfly over lane bits {0,1,3}; no DS traffic
        s0 = red8(s0);  s1 = red8(s1);  s2 = red8(s2);  s3 = red8(s3);

        // static 2-level select of this lane's output sum (lane&3 == ks&3)
        const float sa  = (lane & 1) ? s1 : s0;
        const float sc  = (lane & 1) ? s3 : s2;
        const float sel = (lane & 2) ? sc : sa;

        hnew = tanhf(xv + sel + bias);

        if (writer) {
            hs[cur ^ 1][out] = hnew;          // other buffer: one barrier suffices
            yb[(size_t)s * Hx + out] = hnew;  // fire-and-forget layer output
        }
        cur ^= 1;
        __syncthreads();
    }

    if (writer) hfin[(size_t)b * Hx + out] = hnew;
}

// ------------------------------------------------------------------
// Launch: GEMM(l0) -> scan(l0) -> GEMM(l1) -> scan(l1), stream-ordered.
// ws: xp scratch (64 MB). d_out[0:B*S*H] doubles as y1 scratch before the
// layer-2 scan overwrites it (we fully rewrite d_out every call).
// ------------------------------------------------------------------
extern "C" void kernel_launch(void* const* d_in, const int* in_sizes, int n_in,
                              void* d_out, int out_size, void* d_ws, size_t ws_size,
                              hipStream_t stream) {
    const float* x    = (const float*)d_in[0];   // [B,S,H]
    const float* h0   = (const float*)d_in[1];   // [L,B,H]
    const float* W_ih = (const float*)d_in[2];   // [L,H,H]
    const float* W_hh = (const float*)d_in[3];   // [L,H,H]
    const float* b_ih = (const float*)d_in[4];   // [L,H]
    const float* b_hh = (const float*)d_in[5];   // [L,H]

    float* out    = (float*)d_out;                       // [B,S,H]
    float* finals = out + (size_t)Bx * Sx * Hx;          // [L,B,H]
    float* xp     = (float*)d_ws;                        // [B,S,H] scratch

    const dim3 ggrid(Bx * Sx / GBM, Hx / GBN);           // (1024, 4)

    // Layer 0
    gemm_xp<<<ggrid, 256, 0, stream>>>(x, W_ih, b_ih, xp);
    rnn_scan<<<Bx, 512, 0, stream>>>(xp, h0, W_hh, b_hh,
                                     out /* y1 scratch */, finals);
    // Layer 1
    gemm_xp<<<ggrid, 256, 0, stream>>>(out, W_ih + Hx * Hx, b_ih + Hx, xp);
    rnn_scan<<<Bx, 512, 0, stream>>>(xp, h0 + (size_t)Bx * Hx,
                                     W_hh + Hx * Hx, b_hh + Hx,
                                     out, finals + (size_t)Bx * Hx);
}

// Round 5
// 3717.675 us; speedup vs baseline: 1.4529x; 1.0308x over previous
//
#include <hip/hip_runtime.h>
#include <cstddef>

// Problem dims (fixed by the reference)
#define Bx 32
#define Sx 2048
#define Hx 256
#define Lx 2

// ------------------------------------------------------------------
// GEMM: C[m,n] = sum_k A[m,k] * W[n,k] + bias[n]   (unchanged; ~180 us,
// not the bottleneck while scans are >700 us)
// ------------------------------------------------------------------
#define GBM 64
#define GBN 64
#define GBK 32

__global__ __launch_bounds__(256) void gemm_xp(
    const float* __restrict__ A,
    const float* __restrict__ W,
    const float* __restrict__ bias,
    float* __restrict__ C)
{
    __shared__ float As[GBK][GBM + 1];
    __shared__ float Ws[GBK][GBN + 1];

    const int tid = threadIdx.x;
    const int tx  = tid & 15;
    const int ty  = tid >> 4;
    const int m0  = blockIdx.x * GBM;
    const int n0  = blockIdx.y * GBN;
    const int r   = tid >> 3;
    const int c4  = tid & 7;

    float acc[4][4] = {};

    for (int k0 = 0; k0 < Hx; k0 += GBK) {
        const float4 a0 = *(const float4*)(A + (size_t)(m0 + r)      * Hx + k0 + c4 * 4);
        const float4 a1 = *(const float4*)(A + (size_t)(m0 + r + 32) * Hx + k0 + c4 * 4);
        const float4 w0 = *(const float4*)(W + (size_t)(n0 + r)      * Hx + k0 + c4 * 4);
        const float4 w1 = *(const float4*)(W + (size_t)(n0 + r + 32) * Hx + k0 + c4 * 4);

        __syncthreads();

        As[c4 * 4 + 0][r] = a0.x;  As[c4 * 4 + 1][r] = a0.y;
        As[c4 * 4 + 2][r] = a0.z;  As[c4 * 4 + 3][r] = a0.w;
        As[c4 * 4 + 0][r + 32] = a1.x;  As[c4 * 4 + 1][r + 32] = a1.y;
        As[c4 * 4 + 2][r + 32] = a1.z;  As[c4 * 4 + 3][r + 32] = a1.w;

        Ws[c4 * 4 + 0][r] = w0.x;  Ws[c4 * 4 + 1][r] = w0.y;
        Ws[c4 * 4 + 2][r] = w0.z;  Ws[c4 * 4 + 3][r] = w0.w;
        Ws[c4 * 4 + 0][r + 32] = w1.x;  Ws[c4 * 4 + 1][r + 32] = w1.y;
        Ws[c4 * 4 + 2][r + 32] = w1.z;  Ws[c4 * 4 + 3][r + 32] = w1.w;

        __syncthreads();

        #pragma unroll
        for (int k = 0; k < GBK; ++k) {
            float av[4], wv[4];
            #pragma unroll
            for (int i = 0; i < 4; ++i) av[i] = As[k][ty * 4 + i];
            #pragma unroll
            for (int j = 0; j < 4; ++j) wv[j] = Ws[k][tx * 4 + j];
            #pragma unroll
            for (int i = 0; i < 4; ++i)
                #pragma unroll
                for (int j = 0; j < 4; ++j)
                    acc[i][j] = fmaf(av[i], wv[j], acc[i][j]);
        }
    }

    const float4 bv = *(const float4*)(bias + n0 + tx * 4);
    #pragma unroll
    for (int i = 0; i < 4; ++i) {
        float4 o;
        o.x = acc[i][0] + bv.x;
        o.y = acc[i][1] + bv.y;
        o.z = acc[i][2] + bv.z;
        o.w = acc[i][3] + bv.w;
        *(float4*)(C + (size_t)(m0 + ty * 4 + i) * Hx + n0 + tx * 4) = o;
    }
}

// ------------------------------------------------------------------
// DPP butterfly helpers: reduction entirely on the VALU (no DS pipe).
//   xor1 : quad_perm [1,0,3,2] -> ctrl 0xB1
//   xor2 : quad_perm [2,3,0,1] -> ctrl 0x4E
//   xor8 : row_ror:8           -> ctrl 0x128
// ------------------------------------------------------------------
template <int CTRL>
__device__ __forceinline__ float dpp_xadd(float x) {
    int xi = __builtin_bit_cast(int, x);
    int yi = __builtin_amdgcn_update_dpp(0, xi, CTRL, 0xF, 0xF, true);
    return x + __builtin_bit_cast(float, yi);
}
__device__ __forceinline__ float red8(float s) {
    s = dpp_xadd<0xB1>(s);    // + lane^1
    s = dpp_xadd<0x4E>(s);    // + lane^2
    s = dpp_xadd<0x128>(s);   // + lane^8
    return s;
}

// Opaque register pin: makes v the output of an (empty) asm, so the
// compiler CANNOT rematerialize/sink the load that produced it — the
// round-3/4 failure mode (VGPR=100/104: weights reloaded every step).
__device__ __forceinline__ void pin4(float4 &v) {
    asm volatile("" : "+v"(v.x), "+v"(v.y), "+v"(v.z), "+v"(v.w));
}

// ------------------------------------------------------------------
// Recurrence v4: one WG per batch, 512 threads, 1 barrier/step.
//
// Round-4 evidence: DPP butterfly worked (bank conflicts 0, -300us), but
// VGPR_Count=100 -> the RA is STILL sinking the 32 loop-invariant weight
// loads into the step loop (cost-model choice; waves_per_eu only raised
// the budget). ~1100 cyc/step of avoidable VMEM traffic/latency.
//
// Fix: pin4() every weight fragment after loading. The weights become
// outputs of opaque asm -> not rematerializable -> 128 VGPRs stay live.
// Expected total ~170 VGPR < 256 budget at 2 waves/SIMD.
// ------------------------------------------------------------------
__global__ __launch_bounds__(512)
__attribute__((amdgpu_waves_per_eu(2, 2)))
void rnn_scan(
    const float* __restrict__ xp,    // [B,S,H] precomputed x@W_ih^T + b_ih
    const float* __restrict__ h0l,   // [B,H]
    const float* __restrict__ Whh,   // [H,H]
    const float* __restrict__ bhh,   // [H]
    float* __restrict__ y,           // [B,S,H]
    float* __restrict__ hfin)        // [B,H]
{
    const int b    = blockIdx.x;
    const int t    = threadIdx.x;
    const int lane = t & 63;
    const int wid  = t >> 6;                               // wave id 0..7
    const int ks   = (lane & 3) | ((lane >> 1) & 4);       // k-slice: bits {0,1,3}
    const int gw   = ((lane >> 2) & 1) | ((lane >> 3) & 6);// group-in-wave: bits {2,4,5}
    const int g    = wid * 8 + gw;                         // output quad 0..63
    const int out  = g * 4 + (lane & 3);                   // output this lane finalizes
    const bool writer = (lane & 8) == 0;                   // ks < 4

    // Weights: wq[o][j] = Whh[g*4+o][ks*32 + ((j+ks)&7)*4 .. +3]
    // (pre-rotated so the LDS h-reads below are conflict-free with static
    //  register indexing). 32 float4 = 128 VGPRs, pinned by pin4().
    float4 wq[4][8];
    #pragma unroll
    for (int o = 0; o < 4; ++o) {
        const float* wrow = Whh + (size_t)(g * 4 + o) * Hx + ks * 32;
        #pragma unroll
        for (int j = 0; j < 8; ++j) {
            wq[o][j] = *(const float4*)(wrow + ((j + ks) & 7) * 4);
            pin4(wq[o][j]);          // forbid remat/sink of this load
        }
    }

    __shared__ float hs[2][Hx];
    if (t < Hx) hs[0][t] = h0l[(size_t)b * Hx + t];
    const float bias = bhh[out];
    __syncthreads();

    const float* xpb = xp + (size_t)b * Sx * Hx;
    float*       yb  = y  + (size_t)b * Sx * Hx;

    // 2-deep xp prefetch (covers L2/HBM latency against ~850-cy steps)
    float xv_n1 = xpb[out];
    float xv_n2 = xpb[(size_t)Hx + out];
    float hnew  = 0.0f;
    int   cur   = 0;

    const int rotbase = ks * 128;    // byte offset of this lane's k-slice in hs

    for (int s = 0; s < Sx; ++s) {
        const float xv = xv_n1;
        xv_n1 = xv_n2;
        if (s + 2 < Sx) xv_n2 = xpb[(size_t)(s + 2) * Hx + out];

        // 8 rotated, conflict-free ds_read_b128 of this lane's 128-float slice
        const char* hbase = (const char*)(hs[cur]) + rotbase;
        float4 h4[8];
        #pragma unroll
        for (int j = 0; j < 8; ++j)
            h4[j] = *(const float4*)(hbase + (((j + ks) & 7) << 4));

        float4 a0 = make_float4(0.f,0.f,0.f,0.f);
        float4 a1 = make_float4(0.f,0.f,0.f,0.f);
        float4 a2 = make_float4(0.f,0.f,0.f,0.f);
        float4 a3 = make_float4(0.f,0.f,0.f,0.f);
        #pragma unroll
        for (int j = 0; j < 8; ++j) {
            const float4 hh = h4[j];
            a0.x = fmaf(wq[0][j].x, hh.x, a0.x);
            a0.y = fmaf(wq[0][j].y, hh.y, a0.y);
            a0.z = fmaf(wq[0][j].z, hh.z, a0.z);
            a0.w = fmaf(wq[0][j].w, hh.w, a0.w);
            a1.x = fmaf(wq[1][j].x, hh.x, a1.x);
            a1.y = fmaf(wq[1][j].y, hh.y, a1.y);
            a1.z = fmaf(wq[1][j].z, hh.z, a1.z);
            a1.w = fmaf(wq[1][j].w, hh.w, a1.w);
            a2.x = fmaf(wq[2][j].x, hh.x, a2.x);
            a2.y = fmaf(wq[2][j].y, hh.y, a2.y);
            a2.z = fmaf(wq[2][j].z, hh.z, a2.z);
            a2.w = fmaf(wq[2][j].w, hh.w, a2.w);
            a3.x = fmaf(wq[3][j].x, hh.x, a3.x);
            a3.y = fmaf(wq[3][j].y, hh.y, a3.y);
            a3.z = fmaf(wq[3][j].z, hh.z, a3.z);
            a3.w = fmaf(wq[3][j].w, hh.w, a3.w);
        }
        float s0 = (a0.x + a0.y) + (a0.z + a0.w);
        float s1 = (a1.x + a1.y) + (a1.z + a1.w);
        float s2 = (a2.x + a2.y) + (a2.z + a2.w);
        float s3 = (a3.x + a3.y) + (a3.z + a3.w);

        // VALU-only butterfly over lane bits {0,1,3}; no DS traffic
        s0 = red8(s0);  s1 = red8(s1);  s2 = red8(s2);  s3 = red8(s3);

        // static 2-level select of this lane's output sum (lane&3 == ks&3)
        const float sa  = (lane & 1) ? s1 : s0;
        const float sc  = (lane & 1) ? s3 : s2;
        const float sel = (lane & 2) ? sc : sa;

        hnew = tanhf(xv + sel + bias);

        if (writer) {
            hs[cur ^ 1][out] = hnew;          // other buffer: one barrier suffices
            yb[(size_t)s * Hx + out] = hnew;  // fire-and-forget layer output
        }
        cur ^= 1;
        __syncthreads();
    }

    if (writer) hfin[(size_t)b * Hx + out] = hnew;
}

// ------------------------------------------------------------------
// Launch: GEMM(l0) -> scan(l0) -> GEMM(l1) -> scan(l1), stream-ordered.
// ws: xp scratch (64 MB). d_out[0:B*S*H] doubles as y1 scratch before the
// layer-2 scan overwrites it (we fully rewrite d_out every call).
// ------------------------------------------------------------------
extern "C" void kernel_launch(void* const* d_in, const int* in_sizes, int n_in,
                              void* d_out, int out_size, void* d_ws, size_t ws_size,
                              hipStream_t stream) {
    const float* x    = (const float*)d_in[0];   // [B,S,H]
    const float* h0   = (const float*)d_in[1];   // [L,B,H]
    const float* W_ih = (const float*)d_in[2];   // [L,H,H]
    const float* W_hh = (const float*)d_in[3];   // [L,H,H]
    const float* b_ih = (const float*)d_in[4];   // [L,H]
    const float* b_hh = (const float*)d_in[5];   // [L,H]

    float* out    = (float*)d_out;                       // [B,S,H]
    float* finals = out + (size_t)Bx * Sx * Hx;          // [L,B,H]
    float* xp     = (float*)d_ws;                        // [B,S,H] scratch

    const dim3 ggrid(Bx * Sx / GBM, Hx / GBN);           // (1024, 4)

    // Layer 0
    gemm_xp<<<ggrid, 256, 0, stream>>>(x, W_ih, b_ih, xp);
    rnn_scan<<<Bx, 512, 0, stream>>>(xp, h0, W_hh, b_hh,
                                     out /* y1 scratch */, finals);
    // Layer 1
    gemm_xp<<<ggrid, 256, 0, stream>>>(out, W_ih + Hx * Hx, b_ih + Hx, xp);
    rnn_scan<<<Bx, 512, 0, stream>>>(xp, h0 + (size_t)Bx * Hx,
                                     W_hh + Hx * Hx, b_hh + Hx,
                                     out, finals + (size_t)Bx * Hx);
}

// Round 7
// 3149.556 us; speedup vs baseline: 1.7150x; 1.1804x over previous
//
#include <hip/hip_runtime.h>
#include <cstddef>

// Problem dims (fixed by the reference)
#define Bx 32
#define Sx 2048
#define Hx 256
#define Lx 2

// ------------------------------------------------------------------
// GEMM: C[m,n] = sum_k A[m,k] * W[n,k] + bias[n]   (unchanged; ~180 us,
// not the bottleneck while scans are >700 us)
// ------------------------------------------------------------------
#define GBM 64
#define GBN 64
#define GBK 32

__global__ __launch_bounds__(256) void gemm_xp(
    const float* __restrict__ A,
    const float* __restrict__ W,
    const float* __restrict__ bias,
    float* __restrict__ C)
{
    __shared__ float As[GBK][GBM + 1];
    __shared__ float Ws[GBK][GBN + 1];

    const int tid = threadIdx.x;
    const int tx  = tid & 15;
    const int ty  = tid >> 4;
    const int m0  = blockIdx.x * GBM;
    const int n0  = blockIdx.y * GBN;
    const int r   = tid >> 3;
    const int c4  = tid & 7;

    float acc[4][4] = {};

    for (int k0 = 0; k0 < Hx; k0 += GBK) {
        const float4 a0 = *(const float4*)(A + (size_t)(m0 + r)      * Hx + k0 + c4 * 4);
        const float4 a1 = *(const float4*)(A + (size_t)(m0 + r + 32) * Hx + k0 + c4 * 4);
        const float4 w0 = *(const float4*)(W + (size_t)(n0 + r)      * Hx + k0 + c4 * 4);
        const float4 w1 = *(const float4*)(W + (size_t)(n0 + r + 32) * Hx + k0 + c4 * 4);

        __syncthreads();

        As[c4 * 4 + 0][r] = a0.x;  As[c4 * 4 + 1][r] = a0.y;
        As[c4 * 4 + 2][r] = a0.z;  As[c4 * 4 + 3][r] = a0.w;
        As[c4 * 4 + 0][r + 32] = a1.x;  As[c4 * 4 + 1][r + 32] = a1.y;
        As[c4 * 4 + 2][r + 32] = a1.z;  As[c4 * 4 + 3][r + 32] = a1.w;

        Ws[c4 * 4 + 0][r] = w0.x;  Ws[c4 * 4 + 1][r] = w0.y;
        Ws[c4 * 4 + 2][r] = w0.z;  Ws[c4 * 4 + 3][r] = w0.w;
        Ws[c4 * 4 + 0][r + 32] = w1.x;  Ws[c4 * 4 + 1][r + 32] = w1.y;
        Ws[c4 * 4 + 2][r + 32] = w1.z;  Ws[c4 * 4 + 3][r + 32] = w1.w;

        __syncthreads();

        #pragma unroll
        for (int k = 0; k < GBK; ++k) {
            float av[4], wv[4];
            #pragma unroll
            for (int i = 0; i < 4; ++i) av[i] = As[k][ty * 4 + i];
            #pragma unroll
            for (int j = 0; j < 4; ++j) wv[j] = Ws[k][tx * 4 + j];
            #pragma unroll
            for (int i = 0; i < 4; ++i)
                #pragma unroll
                for (int j = 0; j < 4; ++j)
                    acc[i][j] = fmaf(av[i], wv[j], acc[i][j]);
        }
    }

    const float4 bv = *(const float4*)(bias + n0 + tx * 4);
    #pragma unroll
    for (int i = 0; i < 4; ++i) {
        float4 o;
        o.x = acc[i][0] + bv.x;
        o.y = acc[i][1] + bv.y;
        o.z = acc[i][2] + bv.z;
        o.w = acc[i][3] + bv.w;
        *(float4*)(C + (size_t)(m0 + ty * 4 + i) * Hx + n0 + tx * 4) = o;
    }
}

// ------------------------------------------------------------------
// DPP butterfly helpers: reduction entirely on the VALU (no DS pipe).
// ------------------------------------------------------------------
template <int CTRL>
__device__ __forceinline__ float dpp_xadd(float x) {
    int xi = __builtin_bit_cast(int, x);
    int yi = __builtin_amdgcn_update_dpp(0, xi, CTRL, 0xF, 0xF, true);
    return x + __builtin_bit_cast(float, yi);
}
__device__ __forceinline__ float red8(float s) {
    s = dpp_xadd<0xB1>(s);    // + lane^1  (quad_perm [1,0,3,2])
    s = dpp_xadd<0x4E>(s);    // + lane^2  (quad_perm [2,3,0,1])
    s = dpp_xadd<0x128>(s);   // + lane^8  (row_ror:8)
    return s;
}

// Opaque register pin: "+v" REQUIRES arch VGPRs at this program point.
// Used INSIDE the step loop: if the RA banishes the weights to AGPRs it
// must now pay accvgpr_read+write every iteration, flipping its cost
// model toward keeping them in v-regs (round-5 failure mode: pin at init
// only -> values spilled to AGPRs, 128 accvgpr_read/step VALU tax).
__device__ __forceinline__ void pin4(float4 &v) {
    asm volatile("" : "+v"(v.x), "+v"(v.y), "+v"(v.z), "+v"(v.w));
}

// One recurrence step against the LDS h-buffer at compile-time byte
// offset OFF (0 = buffer 0, 1024 = buffer 1). va[] are loop-invariant
// rotated addresses into buffer 0 -> zero in-loop address VALU.
template <int OFF>
__device__ __forceinline__ float step_phase(const float4 (&wq)[4][8],
                                            const char* const (&va)[8],
                                            float xv, float bias, int lane)
{
    float4 h[8];
    #pragma unroll
    for (int j = 0; j < 8; ++j)
        h[j] = *(const float4*)(va[j] + OFF);   // conflict-free ds_read_b128

    float s0 = 0.f, s1 = 0.f, s2 = 0.f, s3 = 0.f;
    #pragma unroll
    for (int j = 0; j < 8; ++j) {
        // component-major order: each accumulator's FMAs are 4 insts apart
        // (8 cyc > 4-cyc FMA latency) -> no dependency stalls.
        s0 = fmaf(wq[0][j].x, h[j].x, s0);
        s1 = fmaf(wq[1][j].x, h[j].x, s1);
        s2 = fmaf(wq[2][j].x, h[j].x, s2);
        s3 = fmaf(wq[3][j].x, h[j].x, s3);
        s0 = fmaf(wq[0][j].y, h[j].y, s0);
        s1 = fmaf(wq[1][j].y, h[j].y, s1);
        s2 = fmaf(wq[2][j].y, h[j].y, s2);
        s3 = fmaf(wq[3][j].y, h[j].y, s3);
        s0 = fmaf(wq[0][j].z, h[j].z, s0);
        s1 = fmaf(wq[1][j].z, h[j].z, s1);
        s2 = fmaf(wq[2][j].z, h[j].z, s2);
        s3 = fmaf(wq[3][j].z, h[j].z, s3);
        s0 = fmaf(wq[0][j].w, h[j].w, s0);
        s1 = fmaf(wq[1][j].w, h[j].w, s1);
        s2 = fmaf(wq[2][j].w, h[j].w, s2);
        s3 = fmaf(wq[3][j].w, h[j].w, s3);
    }

    // VALU-only butterfly over lane bits {0,1,3}
    s0 = red8(s0);  s1 = red8(s1);  s2 = red8(s2);  s3 = red8(s3);

    // static select of this lane's output (lane&3 == ks&3)
    const float sa  = (lane & 1) ? s1 : s0;
    const float sc  = (lane & 1) ? s3 : s2;
    const float sel = (lane & 2) ? sc : sa;

    return tanhf(xv + sel + bias);
}

// ------------------------------------------------------------------
// Recurrence v5: one WG per batch, 512 threads, 1 barrier/step.
// Layout (proven r3-r5): k-slice ks on lane bits {0,1,3}, output-quad on
// bits {2,4,5}; rotated LDS reads -> 0 bank conflicts; DPP reduce.
// New this round: in-loop weight pin, precomputed LDS addresses, 2x
// unroll for compile-time double-buffer offsets, scalar accumulators.
// ------------------------------------------------------------------
__global__ __launch_bounds__(512)
__attribute__((amdgpu_waves_per_eu(2, 2)))
void rnn_scan(
    const float* __restrict__ xp,    // [B,S,H] precomputed x@W_ih^T + b_ih
    const float* __restrict__ h0l,   // [B,H]
    const float* __restrict__ Whh,   // [H,H]
    const float* __restrict__ bhh,   // [H]
    float* __restrict__ y,           // [B,S,H]
    float* __restrict__ hfin)        // [B,H]
{
    const int b    = blockIdx.x;
    const int t    = threadIdx.x;
    const int lane = t & 63;
    const int wid  = t >> 6;                               // wave id 0..7
    const int ks   = (lane & 3) | ((lane >> 1) & 4);       // k-slice: bits {0,1,3}
    const int gw   = ((lane >> 2) & 1) | ((lane >> 3) & 6);// group-in-wave: bits {2,4,5}
    const int g    = wid * 8 + gw;                         // output quad 0..63
    const int out  = g * 4 + (lane & 3);                   // output this lane finalizes
    const bool writer = (lane & 8) == 0;                   // ks < 4

    // Weights: wq[o][j] = Whh[g*4+o][ks*32 + ((j+ks)&7)*4 .. +3]
    // (pre-rotated to pair with the rotated LDS addresses below).
    float4 wq[4][8];
    #pragma unroll
    for (int o = 0; o < 4; ++o) {
        const float* wrow = Whh + (size_t)(g * 4 + o) * Hx + ks * 32;
        #pragma unroll
        for (int j = 0; j < 8; ++j)
            wq[o][j] = *(const float4*)(wrow + ((j + ks) & 7) * 4);
    }

    __shared__ float hs[2][Hx];                // buf1 = buf0 + 1024 bytes
    if (t < Hx) hs[0][t] = h0l[(size_t)b * Hx + t];
    const float bias = bhh[out];
    __syncthreads();

    // Loop-invariant rotated LDS addresses (buffer 0); buffer 1 via +1024 imm.
    const char* va[8];
    {
        const char* hb0 = (const char*)(&hs[0][0]) + ks * 128;
        #pragma unroll
        for (int j = 0; j < 8; ++j)
            va[j] = hb0 + (((j + ks) & 7) << 4);
    }

    const float* xpb = xp + (size_t)b * Sx * Hx;
    float*       yb  = y  + (size_t)b * Sx * Hx;

    // 2-deep xp prefetch
    float xv_n1 = xpb[out];
    float xv_n2 = xpb[(size_t)Hx + out];
    float hnew  = 0.0f;

    for (int s = 0; s < Sx; s += 2) {
        // Re-pin weights every iteration: forces arch-VGPR residency here.
        #pragma unroll
        for (int o = 0; o < 4; ++o)
            #pragma unroll
            for (int j = 0; j < 8; ++j)
                pin4(wq[o][j]);

        // ---- phase 0: read buf0, write buf1 (step s) ----
        {
            const float xv = xv_n1;
            xv_n1 = xv_n2;
            if (s + 2 < Sx) xv_n2 = xpb[(size_t)(s + 2) * Hx + out];

            hnew = step_phase<0>(wq, va, xv, bias, lane);
            if (writer) {
                hs[1][out] = hnew;
                yb[(size_t)s * Hx + out] = hnew;
            }
            __syncthreads();
        }

        // ---- phase 1: read buf1 (+1024 imm), write buf0 (step s+1) ----
        {
            const float xv = xv_n1;
            xv_n1 = xv_n2;
            if (s + 3 < Sx) xv_n2 = xpb[(size_t)(s + 3) * Hx + out];

            hnew = step_phase<1024>(wq, va, xv, bias, lane);
            if (writer) {
                hs[0][out] = hnew;
                yb[(size_t)(s + 1) * Hx + out] = hnew;
            }
            __syncthreads();
        }
    }

    if (writer) hfin[(size_t)b * Hx + out] = hnew;
}

// ------------------------------------------------------------------
// Launch: GEMM(l0) -> scan(l0) -> GEMM(l1) -> scan(l1), stream-ordered.
// ws: xp scratch (64 MB). d_out[0:B*S*H] doubles as y1 scratch before the
// layer-2 scan overwrites it (we fully rewrite d_out every call).
// ------------------------------------------------------------------
extern "C" void kernel_launch(void* const* d_in, const int* in_sizes, int n_in,
                              void* d_out, int out_size, void* d_ws, size_t ws_size,
                              hipStream_t stream) {
    const float* x    = (const float*)d_in[0];   // [B,S,H]
    const float* h0   = (const float*)d_in[1];   // [L,B,H]
    const float* W_ih = (const float*)d_in[2];   // [L,H,H]
    const float* W_hh = (const float*)d_in[3];   // [L,H,H]
    const float* b_ih = (const float*)d_in[4];   // [L,H]
    const float* b_hh = (const float*)d_in[5];   // [L,H]

    float* out    = (float*)d_out;                       // [B,S,H]
    float* finals = out + (size_t)Bx * Sx * Hx;          // [L,B,H]
    float* xp     = (float*)d_ws;                        // [B,S,H] scratch

    const dim3 ggrid(Bx * Sx / GBM, Hx / GBN);           // (1024, 4)

    // Layer 0
    gemm_xp<<<ggrid, 256, 0, stream>>>(x, W_ih, b_ih, xp);
    rnn_scan<<<Bx, 512, 0, stream>>>(xp, h0, W_hh, b_hh,
                                     out /* y1 scratch */, finals);
    // Layer 1
    gemm_xp<<<ggrid, 256, 0, stream>>>(out, W_ih + Hx * Hx, b_ih + Hx, xp);
    rnn_scan<<<Bx, 512, 0, stream>>>(xp, h0 + (size_t)Bx * Hx,
                                     W_hh + Hx * Hx, b_hh + Hx,
                                     out, finals + (size_t)Bx * Hx);
}